// Round 4
// baseline (246.210 us; speedup 1.0000x reference)
//
#include <hip/hip_runtime.h>
#include <hip/hip_bf16.h>

#define NDRUG 846
#define EDIM 256
#define NS 128
#define XOFF (NDRUG * EDIM)          // x region in d_out (gnn1 slot, f32)
#define B2SOFF (2 * NDRUG * EDIM - NS)  // b2sum in tail of x region
#define NLINBLK 14                   // lin_gemm M-tiles of 64
#define NSTATBLK 54                  // bn_stats m-tiles of 16

typedef short s8v __attribute__((ext_vector_type(8)));
typedef __bf16 b8v __attribute__((ext_vector_type(8)));
typedef float f32x4 __attribute__((ext_vector_type(4)));

static __device__ __forceinline__ short bfs(float f) {
  __bf16 h = (__bf16)f;
  return __builtin_bit_cast(short, h);
}

template <typename V>
static __device__ __forceinline__ auto mfma_impl(V a, V b, f32x4 c, int)
    -> decltype(__builtin_amdgcn_mfma_f32_16x16x32_bf16(a, b, c, 0, 0, 0)) {
  return __builtin_amdgcn_mfma_f32_16x16x32_bf16(a, b, c, 0, 0, 0);
}
template <typename V>
static __device__ __forceinline__ f32x4 mfma_impl(V a, V b, f32x4 c, long) {
  b8v ab = __builtin_bit_cast(b8v, a);
  b8v bb = __builtin_bit_cast(b8v, b);
  return __builtin_amdgcn_mfma_f32_16x16x32_bf16(ab, bb, c, 0, 0, 0);
}
static __device__ __forceinline__ f32x4 mfma16(s8v a, s8v b, f32x4 c) {
  return mfma_impl(a, b, c, 0);
}

// ---------------- b2 column-sum precompute (block-invariant) ----------------
__global__ __launch_bounds__(64) void b2prep(const float* __restrict__ b2,
                                             float* __restrict__ b2s) {
  const int n = blockIdx.x;
  const int t = threadIdx.x;
  const float4 v4 = *(const float4*)(b2 + n * EDIM + 4 * t);
  float v = v4.x + v4.y + v4.z + v4.w;
#pragma unroll
  for (int off = 1; off < 64; off <<= 1) v += __shfl_xor(v, off);
  if (t == 0) b2s[n] = v;
}

// ---------------- main per-drug kernel ----------------
__global__ __launch_bounds__(512, 4) void gnn_main(
    const int* __restrict__ drug_name,
    const int* __restrict__ adj_tail,
    const int* __restrict__ adj_relation,
    const float* __restrict__ drug_table,
    const float* __restrict__ rela_table,
    const float* __restrict__ ent_table,
    const float* __restrict__ W1,
    const float* __restrict__ b1,
    const float* __restrict__ W2,
    const float* __restrict__ b2s,
    float* __restrict__ ws_we) {
  __shared__ __align__(16) unsigned short s_ab[NS * EDIM];  // 64KB dr tile / scratch
  __shared__ float s_d[EDIM];
  __shared__ int s_tail[NS];
  __shared__ float s_w2sum[EDIM];
  __shared__ float s_scorep[8][NS];
  __shared__ float s_attn[NS];

  const int b = blockIdx.x;
  const int tid = threadIdx.x;
  const int w = tid >> 6;
  const int l = tid & 63;
  const int g = l >> 4;
  const int lr = l & 15;
  const int rg = tid >> 4;   // 0..31 (W2 rowsum row group)
  const int lc = tid & 15;   // W2 rowsum col group

  if (tid < EDIM) {
    const int dn = drug_name[b];
    s_d[tid] = drug_table[(long)dn * EDIM + tid];
  } else if (tid < EDIM + NS) {
    s_tail[tid - EDIM] = adj_tail[b * NS + (tid - EDIM)];
  }
  __syncthreads();

  // dr[n][e] = d[e] * r[n][e] -> LDS bf16 (XOR-swizzled)
  {
    const int n = tid >> 2;
    const int e0 = (tid & 3) * 64;
    const int rel = adj_relation[b * NS + n];
    const float* rrow = rela_table + (long)rel * EDIM;
    const int swz = (n & 7) << 4;
#pragma unroll
    for (int c = 0; c < 8; ++c) {
      const int e = e0 + c * 8;
      float4 p0 = *(const float4*)(rrow + e);
      float4 p1 = *(const float4*)(rrow + e + 4);
      s8v v;
      v[0] = bfs(p0.x * s_d[e + 0]);
      v[1] = bfs(p0.y * s_d[e + 1]);
      v[2] = bfs(p0.z * s_d[e + 2]);
      v[3] = bfs(p0.w * s_d[e + 3]);
      v[4] = bfs(p1.x * s_d[e + 4]);
      v[5] = bfs(p1.y * s_d[e + 5]);
      v[6] = bfs(p1.z * s_d[e + 6]);
      v[7] = bfs(p1.w * s_d[e + 7]);
      *(s8v*)((char*)s_ab + ((n * 512 + e * 2) ^ swz)) = v;
    }
  }
  __syncthreads();

  // Fused kk-loop: h1 = dr @ W1[b] (MFMA, depth-2 pinned prefetch)
  //              + w2sum[e] = sum_f W2[b][e][f] (independent stream, issued first)
  f32x4 acc[8][2];
#pragma unroll
  for (int mt = 0; mt < 8; ++mt) {
    acc[mt][0] = (f32x4){0.f, 0.f, 0.f, 0.f};
    acc[mt][1] = (f32x4){0.f, 0.f, 0.f, 0.f};
  }
  {
    const float* Wp = W1 + (long)b * EDIM * EDIM;
    const float* W2p = W2 + (long)b * EDIM * EDIM;
    const int col0 = 32 * w + lr;
    const int swz = (lr & 7) << 4;
    float fb[2][16];
    s8v bf0[2], bf1[2];

#define LOADW(buf, kt)                                      \
  do {                                                      \
    const float* pk = Wp + ((kt)*32 + 8 * g) * EDIM + col0; \
    _Pragma("unroll") for (int j = 0; j < 8; ++j) {         \
      (buf)[j] = pk[j * EDIM];                              \
      (buf)[8 + j] = pk[j * EDIM + 16];                     \
    }                                                       \
  } while (0)
#define CVTW(d0, d1, src)                           \
  do {                                              \
    _Pragma("unroll") for (int j = 0; j < 8; ++j) { \
      (d0)[j] = bfs((src)[j]);                      \
      (d1)[j] = bfs((src)[8 + j]);                  \
    }                                               \
  } while (0)

    LOADW(fb[0], 0);
    LOADW(fb[1], 1);
    CVTW(bf0[0], bf1[0], fb[0]);

#pragma unroll
    for (int kk = 0; kk < 8; ++kk) {
      const int c = kk & 1;
      // W2 rows for this kk: issue FIRST so their wait leaves W1 loads in flight
      const float* q = W2p + (32 * kk + rg) * EDIM + lc * 16;
      const float4 q0 = *(const float4*)q;
      const float4 q1 = *(const float4*)(q + 4);
      const float4 q2 = *(const float4*)(q + 8);
      const float4 q3 = *(const float4*)(q + 12);
      if (kk + 2 < 8) LOADW(fb[c], kk + 2);
      __builtin_amdgcn_sched_barrier(0);
      const int kb = (32 * kk + 8 * g) * 2;
#pragma unroll
      for (int mt = 0; mt < 8; ++mt) {
        const int row = 16 * mt + lr;
        s8v af = *(const s8v*)((const char*)s_ab + ((row * 512 + kb) ^ swz));
        acc[mt][0] = mfma16(af, bf0[c], acc[mt][0]);
        acc[mt][1] = mfma16(af, bf1[c], acc[mt][1]);
      }
      __builtin_amdgcn_sched_barrier(0);
      if (kk + 1 < 8) {
        if (c)
          CVTW(bf0[0], bf1[0], fb[0]);
        else
          CVTW(bf0[1], bf1[1], fb[1]);
      }
      // reduce W2 rows for this kk
      float v = q0.x + q0.y + q0.z + q0.w + q1.x + q1.y + q1.z + q1.w +
                q2.x + q2.y + q2.z + q2.w + q3.x + q3.y + q3.z + q3.w;
#pragma unroll
      for (int off = 1; off < 16; off <<= 1) v += __shfl_xor(v, off);
      if (lc == 0) s_w2sum[32 * kk + rg] = v;
    }
#undef LOADW
#undef CVTW
  }
  __syncthreads();  // s_w2sum complete

  // score[n] = sum_f relu(h1[n][f]+b1[n][f]) * w2sum[f]
#pragma unroll
  for (int mt = 0; mt < 8; ++mt) {
#pragma unroll
    for (int jj = 0; jj < 4; ++jj) {
      const int n = 16 * mt + 4 * g + jj;
      const int f0 = 32 * w + lr;
      const int f1 = f0 + 16;
      float v = fmaxf(acc[mt][0][jj] + b1[n * EDIM + f0], 0.f) * s_w2sum[f0] +
                fmaxf(acc[mt][1][jj] + b1[n * EDIM + f1], 0.f) * s_w2sum[f1];
#pragma unroll
      for (int off = 1; off < 16; off <<= 1) v += __shfl_xor(v, off);
      if (lr == 0) s_scorep[w][n] = v;
    }
  }
  __syncthreads();

  // softmax over 128 neighbors (wave 0)
  if (w == 0) {
    float v0 = b2s[l], v1 = b2s[l + 64];
#pragma unroll
    for (int ww = 0; ww < 8; ++ww) {
      v0 += s_scorep[ww][l];
      v1 += s_scorep[ww][l + 64];
    }
    float m = fmaxf(v0, v1);
#pragma unroll
    for (int off = 1; off < 64; off <<= 1) m = fmaxf(m, __shfl_xor(m, off));
    const float e0 = expf(v0 - m), e1 = expf(v1 - m);
    float s = e0 + e1;
#pragma unroll
    for (int off = 1; off < 64; off <<= 1) s += __shfl_xor(s, off);
    const float inv = 1.f / s;
    s_attn[l] = e0 * inv;
    s_attn[l + 64] = e1 * inv;
  }
  __syncthreads();

  // weighted_ent[f] = sum_n attn[n] * ent[tail[n]][f]  (float4, 2-way ILP)
  float* s_scratch = (float*)s_ab;  // dr tile dead; reuse
  {
    const int f4 = tid & 63;
    const int ng = tid >> 6;
    float4 a0 = {0.f, 0.f, 0.f, 0.f}, a1 = {0.f, 0.f, 0.f, 0.f};
#pragma unroll
    for (int i = 0; i < 8; ++i) {
      const int n0 = 16 * ng + i;
      const int n1 = n0 + 8;
      const float4 e0 = *(const float4*)(ent_table + (long)s_tail[n0] * EDIM + 4 * f4);
      const float4 e1 = *(const float4*)(ent_table + (long)s_tail[n1] * EDIM + 4 * f4);
      const float t0 = s_attn[n0], t1 = s_attn[n1];
      a0.x += t0 * e0.x; a0.y += t0 * e0.y; a0.z += t0 * e0.z; a0.w += t0 * e0.w;
      a1.x += t1 * e1.x; a1.y += t1 * e1.y; a1.z += t1 * e1.z; a1.w += t1 * e1.w;
    }
    a0.x += a1.x; a0.y += a1.y; a0.z += a1.z; a0.w += a1.w;
    *(float4*)(s_scratch + ng * 256 + 4 * f4) = a0;
  }
  __syncthreads();

  if (tid < EDIM) {
    float v = 0.f;
#pragma unroll
    for (int ng = 0; ng < 8; ++ng) v += s_scratch[ng * 256 + tid];
    ws_we[(long)b * EDIM + tid] = v;
  }
}

// ---------------- linear layer: x = relu([we|d] @ lin_w + lin_b) ----------------
__global__ __launch_bounds__(512, 4) void lin_gemm(
    const float* __restrict__ ws_we,
    const int* __restrict__ drug_name,
    const float* __restrict__ drug_table,
    const float* __restrict__ lin_w,
    const float* __restrict__ lin_b,
    float* __restrict__ x_out) {
  __shared__ __align__(16) unsigned short s_a[64 * 512];  // 64KB bf16 A-tile, swizzled
  const int blk = blockIdx.x;
  const int m0 = 64 * blk;
  const int tid = threadIdx.x;
  const int w = tid >> 6;
  const int l = tid & 63;
  const int g = l >> 4;
  const int lr = l & 15;

  // stage A rows: [we[m] | d[m]] -> bf16, row stride 1024B, swz ^((r&7)<<4)
  {
    const int r = tid >> 3;       // 0..63
    const int qq = tid & 7;       // 64-col chunk
    const int m = m0 + r;
    const bool valid = m < NDRUG;
    const int c0 = 64 * qq;
    const float* src;
    if (qq < 4) {
      src = ws_we + (long)m * EDIM + c0;
    } else {
      const int dn = valid ? drug_name[m] : 0;
      src = drug_table + (long)dn * EDIM + (c0 - EDIM);
    }
    const int swz = (r & 7) << 4;
#pragma unroll
    for (int u = 0; u < 8; ++u) {
      float4 p0 = valid ? *(const float4*)(src + 8 * u)
                        : (float4){0.f, 0.f, 0.f, 0.f};
      float4 p1 = valid ? *(const float4*)(src + 8 * u + 4)
                        : (float4){0.f, 0.f, 0.f, 0.f};
      s8v v;
      v[0] = bfs(p0.x); v[1] = bfs(p0.y); v[2] = bfs(p0.z); v[3] = bfs(p0.w);
      v[4] = bfs(p1.x); v[5] = bfs(p1.y); v[6] = bfs(p1.z); v[7] = bfs(p1.w);
      *(s8v*)((char*)s_a + ((r * 1024 + (c0 + 8 * u) * 2) ^ swz)) = v;
    }
  }
  __syncthreads();

  f32x4 acc[4][2];
#pragma unroll
  for (int mt = 0; mt < 4; ++mt) {
    acc[mt][0] = (f32x4){0.f, 0.f, 0.f, 0.f};
    acc[mt][1] = (f32x4){0.f, 0.f, 0.f, 0.f};
  }
  {
    const int col0 = 32 * w + lr;
    const int swz = (lr & 7) << 4;
    float fb[2][16];
    s8v bf0[2], bf1[2];
#define LOADL(buf, kt)                                           \
  do {                                                           \
    const float* pk = lin_w + ((kt)*32 + 8 * g) * EDIM + col0;   \
    _Pragma("unroll") for (int j = 0; j < 8; ++j) {              \
      (buf)[j] = pk[j * EDIM];                                   \
      (buf)[8 + j] = pk[j * EDIM + 16];                          \
    }                                                            \
  } while (0)
#define CVTL(d0, d1, src)                           \
  do {                                              \
    _Pragma("unroll") for (int j = 0; j < 8; ++j) { \
      (d0)[j] = bfs((src)[j]);                      \
      (d1)[j] = bfs((src)[8 + j]);                  \
    }                                               \
  } while (0)
    LOADL(fb[0], 0);
    LOADL(fb[1], 1);
    CVTL(bf0[0], bf1[0], fb[0]);
#pragma unroll
    for (int kk = 0; kk < 16; ++kk) {
      const int c = kk & 1;
      if (kk + 2 < 16) LOADL(fb[c], kk + 2);
      __builtin_amdgcn_sched_barrier(0);
      const int kb = (32 * kk + 8 * g) * 2;
#pragma unroll
      for (int mt = 0; mt < 4; ++mt) {
        const int row = 16 * mt + lr;
        s8v af = *(const s8v*)((const char*)s_a + ((row * 1024 + kb) ^ swz));
        acc[mt][0] = mfma16(af, bf0[c], acc[mt][0]);
        acc[mt][1] = mfma16(af, bf1[c], acc[mt][1]);
      }
      __builtin_amdgcn_sched_barrier(0);
      if (kk + 1 < 16) {
        if (c)
          CVTL(bf0[0], bf1[0], fb[0]);
        else
          CVTL(bf0[1], bf1[1], fb[1]);
      }
    }
#undef LOADL
#undef CVTL
  }

  // epilogue: +lin_b, relu, store f32 row-major
#pragma unroll
  for (int mt = 0; mt < 4; ++mt) {
#pragma unroll
    for (int nt = 0; nt < 2; ++nt) {
      const int f = 32 * w + 16 * nt + lr;
#pragma unroll
      for (int jj = 0; jj < 4; ++jj) {
        const int m = m0 + 16 * mt + 4 * g + jj;
        if (m < NDRUG)
          x_out[(long)m * EDIM + f] = fmaxf(acc[mt][nt][jj] + lin_b[f], 0.f);
      }
    }
  }
}

// ---------------- BN: stats partials / finalize / apply ----------------
__global__ __launch_bounds__(256) void bn_stats(const float* __restrict__ x,
                                                float* __restrict__ part) {
  const int mb = blockIdx.x * 16;
  const int f = threadIdx.x;
  float s = 0.f, ss = 0.f;
#pragma unroll
  for (int i = 0; i < 16; ++i) {
    const int m = mb + i;
    if (m < NDRUG) {
      const float v = x[(long)m * EDIM + f];
      s += v;
      ss += v * v;
    }
  }
  part[blockIdx.x * 512 + f] = s;
  part[blockIdx.x * 512 + 256 + f] = ss;
}

__global__ __launch_bounds__(256) void bn_finalize(const float* __restrict__ part,
                                                   const float* __restrict__ gamma,
                                                   const float* __restrict__ beta,
                                                   float* __restrict__ scsh) {
  const int f = threadIdx.x;
  float s = 0.f, ss = 0.f;
  for (int b = 0; b < NSTATBLK; ++b) {
    s += part[b * 512 + f];
    ss += part[b * 512 + 256 + f];
  }
  const float mean = s * (1.f / NDRUG);
  const float var = ss * (1.f / NDRUG) - mean * mean;
  const float sc = rsqrtf(var + 1e-5f) * gamma[f];
  scsh[f] = sc;
  scsh[EDIM + f] = beta[f] - mean * sc;
}

__global__ __launch_bounds__(512) void bn_apply(const float* __restrict__ x,
                                                const float* __restrict__ scsh,
                                                float* __restrict__ out) {
  const int i = blockIdx.x * 512 + threadIdx.x;
  const int f = i & 255;
  out[i] = x[i] * scsh[f] + scsh[EDIM + f];
}

__global__ void tail_kernel(const float* __restrict__ gnn1, const int* __restrict__ idx,
                            float* __restrict__ out) {
  const int total4 = NDRUG * EDIM / 4;
  const float4* s4 = (const float4*)gnn1;
  float4* d4 = (float4*)(out + XOFF);
  for (int i = blockIdx.x * blockDim.x + threadIdx.x; i < total4;
       i += gridDim.x * blockDim.x)
    d4[i] = s4[i];
  if (blockIdx.x == 0 && threadIdx.x == 0) out[2 * NDRUG * EDIM] = (float)idx[0];
}

extern "C" void kernel_launch(void* const* d_in, const int* in_sizes, int n_in,
                              void* d_out, int out_size, void* d_ws, size_t ws_size,
                              hipStream_t stream) {
  const float* gnn1       = (const float*)d_in[0];
  const int*   idx        = (const int*)d_in[1];
  const int*   drug_name  = (const int*)d_in[2];
  const int*   adj_tail   = (const int*)d_in[3];
  const int*   adj_rel    = (const int*)d_in[4];
  const float* drug_table = (const float*)d_in[5];
  const float* rela_table = (const float*)d_in[6];
  const float* ent_table  = (const float*)d_in[7];
  const float* W1         = (const float*)d_in[8];
  const float* b1         = (const float*)d_in[9];
  const float* W2         = (const float*)d_in[10];
  const float* b2         = (const float*)d_in[11];
  const float* lin_w      = (const float*)d_in[12];
  const float* lin_b      = (const float*)d_in[13];
  const float* bn_g       = (const float*)d_in[14];
  const float* bn_b       = (const float*)d_in[15];

  float* out = (float*)d_out;
  float* x    = out + XOFF;      // [846][256] f32 in gnn1 slot (tail rewrites it)
  float* b2s  = out + B2SOFF;    // 128 f32, overwritten later by lin_gemm's x
  float* part = out;             // bn partials in drug_f slot (bn_apply rewrites)
  float* ws_we = (float*)d_ws;   // [846][256] f32
  float* scsh  = (float*)d_ws;   // reuses we region (we dead after lin_gemm)

  // Stream-ordered plan (graph-capture safe, fully rewritten every call):
  // b2prep -> gnn_main -> lin_gemm -> bn_stats -> bn_finalize -> bn_apply -> tail
  b2prep<<<NS, 64, 0, stream>>>(b2, b2s);
  gnn_main<<<NDRUG, 512, 0, stream>>>(drug_name, adj_tail, adj_rel, drug_table,
                                      rela_table, ent_table, W1, b1, W2, b2s,
                                      ws_we);
  lin_gemm<<<NLINBLK, 512, 0, stream>>>(ws_we, drug_name, drug_table, lin_w,
                                        lin_b, x);
  bn_stats<<<NSTATBLK, 256, 0, stream>>>(x, part);
  bn_finalize<<<1, 256, 0, stream>>>(part, bn_g, bn_b, scsh);
  bn_apply<<<(NDRUG * EDIM) / 512, 512, 0, stream>>>(x, scsh, out);
  tail_kernel<<<240, 256, 0, stream>>>(gnn1, idx, out);
}